// Round 1
// 77.614 us; speedup vs baseline: 1.0319x; 1.0319x over previous
//
#include <hip/hip_runtime.h>
#include <math.h>

#define BB 64          // batch
#define CC 16          // children per sample
#define DD 512         // feature dim
#define LL 8192        // CC*DD flattened length
#define EPSV 1e-8f
#define INVT 10.0f     // 1/TEMPERATURE
#define NEGINF_T (-1e31f)   // NEG_INF / TEMPERATURE

// ws layout (floats):
//  [0,     1024)  n2i : ||ci row r||^2   (r = b*16+c)
//  [1024,  2048)  n2j : ||cj row r||^2
//  [2048,  6144)  dj  : raw gathered dots vs cj  [64,64]
//  [6144, 10240)  dk  : raw gathered dots vs ci  [64,64]
//  [10240,10304)  pos : dot(fi, fj) per anchor
#define WS_N2I 0
#define WS_N2J 1024
#define WS_DJ  2048
#define WS_DK  6144
#define WS_POS 10240

__device__ __forceinline__ float dot4(float4 a, float4 b) {
    return a.x * b.x + a.y * b.y + a.z * b.z + a.w * b.w;
}

__device__ __forceinline__ float wave_reduce(float v) {
    #pragma unroll
    for (int off = 32; off; off >>= 1) v += __shfl_down(v, off);
    return v;
}

// ---------------------------------------------------------------------------
// main (fused prep+sim — prep was fully independent of sim, so its blocks now
// ride along in the same dispatch instead of serializing before it):
//   blocks [0,1024)    : sim role. jt=b&15, i=b>>4; raw gathered dots for
//                        j in [4*jt, 4*jt+4). fi register-cached per block.
//   blocks [1024,1536) : norm role. 4 child-row norms per block (1 wave each).
//   blocks [1536,1600) : positive-pair dot for anchor i=b-1536; b==1536 also
//                        zeroes out[0] (final kernel atomically accumulates).
// ---------------------------------------------------------------------------
__global__ __launch_bounds__(256) void ntx_main(const float* __restrict__ ci,
                                                const float* __restrict__ cj,
                                                const int* __restrict__ nj,
                                                const int* __restrict__ nk,
                                                float* __restrict__ ws,
                                                float* __restrict__ out) {
    const int b = blockIdx.x, tid = threadIdx.x;

    if (b < 1024) {
        // ---- sim role ----
        __shared__ int   sidx[2][4][16];     // [side][jj][c]
        __shared__ float red[4][2][4];       // [jj][side][wave]
        const int jt = b & 15;    // 0..15
        const int i  = b >> 4;    // 0..63

        if (tid < 64)        ((int*)sidx)[tid] = nj[i * 1024 + jt * 64 + tid];
        else if (tid < 128)  ((int*)sidx)[tid] = nk[i * 1024 + jt * 64 + (tid - 64)];

        const float4* fi4 = (const float4*)(ci + i * LL);
        float4 fiv[8];
        #pragma unroll
        for (int it = 0; it < 8; ++it) fiv[it] = fi4[tid + 256 * it];

        __syncthreads();

        const int d4   = tid & 127;   // float4 offset within a child row (invariant)
        const int half = tid >> 7;    // c parity handled by this half of the block
        const float4* cj4 = (const float4*)cj;
        const float4* ci4 = (const float4*)ci;

        #pragma unroll
        for (int jj = 0; jj < 4; ++jj) {
            const int j = jt * 4 + jj;
            const float4* bj = cj4 + j * CC * 128;
            const float4* bk = ci4 + j * CC * 128;
            float aj = 0.f, ak = 0.f;
            #pragma unroll
            for (int it = 0; it < 8; ++it) {
                const int c = half + 2 * it;           // (tid + it*256) >> 7
                float4 vj = bj[sidx[0][jj][c] * 128 + d4];
                float4 vk = bk[sidx[1][jj][c] * 128 + d4];
                aj += dot4(fiv[it], vj);
                ak += dot4(fiv[it], vk);
            }
            aj = wave_reduce(aj);
            ak = wave_reduce(ak);
            if ((tid & 63) == 0) { red[jj][0][tid >> 6] = aj; red[jj][1][tid >> 6] = ak; }
        }
        __syncthreads();
        if (tid < 8) {
            const int jj = tid >> 1, side = tid & 1;
            float s = red[jj][side][0] + red[jj][side][1] + red[jj][side][2] + red[jj][side][3];
            ws[(side ? WS_DK : WS_DJ) + i * BB + jt * 4 + jj] = s;
        }
    } else if (b < 1536) {
        // ---- norm role ----
        const int row  = (b - 1024) * 4 + (tid >> 6);   // 0..2047 (first 1024 = ci rows)
        const int lane = tid & 63;
        const int r    = row & 1023;
        const float4* src = (const float4*)(row < 1024 ? ci : cj);
        float4 v1 = src[r * 128 + lane];
        float4 v2 = src[r * 128 + 64 + lane];
        float acc = dot4(v1, v1) + dot4(v2, v2);
        acc = wave_reduce(acc);
        if (lane == 0) ws[(row < 1024 ? WS_N2I : WS_N2J) + r] = acc;
    } else {
        // ---- positive-dot role ----
        __shared__ float red2[4];
        const int i = b - 1536;
        if (b == 1536 && tid == 0) out[0] = 0.f;
        const float4* fi = (const float4*)(ci + i * LL);
        const float4* fj = (const float4*)(cj + i * LL);
        float acc = 0.f;
        #pragma unroll
        for (int it = 0; it < 8; ++it) acc += dot4(fi[tid + 256 * it], fj[tid + 256 * it]);
        acc = wave_reduce(acc);
        if ((tid & 63) == 0) red2[tid >> 6] = acc;
        __syncthreads();
        if (tid == 0) ws[WS_POS + i] = red2[0] + red2[1] + red2[2] + red2[3];
    }
}

// ---------------------------------------------------------------------------
// final: block i, lane j. Normalize raw dots, masked logsumexp over 129
// logits via wave butterfly, atomicAdd loss_i/(2B) into out.
// nj/nk index loads vectorized as int4 (4x16B instead of 16 dwords).
// ---------------------------------------------------------------------------
__global__ __launch_bounds__(64) void ntx_final(const int* __restrict__ pids,
                                                const int* __restrict__ nj,
                                                const int* __restrict__ nk,
                                                const float* __restrict__ ws,
                                                float* __restrict__ out) {
    const int i = blockIdx.x, j = threadIdx.x;
    __shared__ float sn2i[1024], sn2j[1024];
    const float4* n2i4 = (const float4*)(ws + WS_N2I);
    const float4* n2j4 = (const float4*)(ws + WS_N2J);
    #pragma unroll
    for (int t = 0; t < 4; ++t) {
        ((float4*)sn2i)[j + 64 * t] = n2i4[j + 64 * t];
        ((float4*)sn2j)[j + 64 * t] = n2j4[j + 64 * t];
    }
    __syncthreads();

    float si = 0.f, sjf = 0.f;
    #pragma unroll
    for (int c = 0; c < CC; ++c) { si += sn2i[i * CC + c]; sjf += sn2j[i * CC + c]; }
    const float ni = fmaxf(sqrtf(si), EPSV);
    const float l0 = ws[WS_POS + i] / (ni * fmaxf(sqrtf(sjf), EPSV)) * INVT;

    const int4* nj4 = (const int4*)(nj + (i * BB + j) * CC);
    const int4* nk4 = (const int4*)(nk + (i * BB + j) * CC);
    float gj = 0.f, gk = 0.f;
    #pragma unroll
    for (int t = 0; t < 4; ++t) {
        int4 a = nj4[t];
        gj += sn2j[j * CC + a.x] + sn2j[j * CC + a.y] + sn2j[j * CC + a.z] + sn2j[j * CC + a.w];
        int4 bq = nk4[t];
        gk += sn2i[j * CC + bq.x] + sn2i[j * CC + bq.y] + sn2i[j * CC + bq.z] + sn2i[j * CC + bq.w];
    }

    const bool valid = (j != i) && (pids[j] != pids[i]);
    float lj = NEGINF_T, lk = NEGINF_T;
    if (valid) {
        const float inv = INVT / ni;
        lj = ws[WS_DJ + i * BB + j] / fmaxf(sqrtf(gj), EPSV) * inv;
        lk = ws[WS_DK + i * BB + j] / fmaxf(sqrtf(gk), EPSV) * inv;
    }

    float m = fmaxf(lj, lk);
    #pragma unroll
    for (int off = 32; off; off >>= 1) m = fmaxf(m, __shfl_xor(m, off));
    m = fmaxf(m, l0);

    float s = __expf(lj - m) + __expf(lk - m);
    s = wave_reduce(s);
    if (j == 0) {
        s += __expf(l0 - m);
        const float loss_i = -l0 + m + __logf(s);
        atomicAdd(out, loss_i * (1.0f / (2.0f * BB)));
    }
}

// ---------------------------------------------------------------------------
extern "C" void kernel_launch(void* const* d_in, const int* in_sizes, int n_in,
                              void* d_out, int out_size, void* d_ws, size_t ws_size,
                              hipStream_t stream) {
    const float* ci  = (const float*)d_in[0];
    const float* cj  = (const float*)d_in[1];
    const int*  pids = (const int*) d_in[2];
    const int*  nj   = (const int*) d_in[3];
    const int*  nk   = (const int*) d_in[4];
    float* ws  = (float*)d_ws;
    float* out = (float*)d_out;

    ntx_main<<<1600, 256, 0, stream>>>(ci, cj, nj, nk, ws, out);
    ntx_final<<<BB, 64, 0, stream>>>(pids, nj, nk, ws, out);
}